// Round 13
// baseline (60.565 us; speedup 1.0000x reference)
//
#include <hip/hip_runtime.h>
#include <hip/hip_bf16.h>

// AdaptiveTripletLoss on MI355X (gfx950).
// R13: k_gemm re-tiled for cross-block TLP: 128x256 tiles, 256-thread/4-wave
// blocks, BK=32 dbuf, 55KB LDS -> EXACTLY 2 independent blocks/CU (512
// blocks, all co-resident, no tail). R9's 8-wave lockstep block exposed
// ds_read+stage phases (probe: 5.3+7.7+8.3us serial = 22); two unsynced
// blocks/CU let one block's MFMA hide the other's memory phases (m97
// mechanism). Counted vmcnt(6), never 0 in loop. BK=32 swizzle = R4's
// verified pair. k_stats/k_row/fin1/fin2 unchanged from R12.

#define NN 4096
#define DD 512
#define NCLS 64

typedef __bf16 bf16x8 __attribute__((ext_vector_type(8)));
typedef float f32x4 __attribute__((ext_vector_type(4)));

__device__ __forceinline__ void gload_lds16(const void* g, void* l) {
  __builtin_amdgcn_global_load_lds(
      (const __attribute__((address_space(1))) void*)g,
      (__attribute__((address_space(3))) void*)l, 16, 0, 0);
}

// ---------------- kernel 1: per-class stats (4 blocks/class) ----------------
__global__ __launch_bounds__(512) void k_stats(
    const float* __restrict__ feats, const int* __restrict__ labels,
    float* __restrict__ counts, float* __restrict__ cmean,
    float* __restrict__ pvar) {
  __shared__ __align__(16) int slab[NN];
  __shared__ int list[NN];
  __shared__ int chunk_off[64];
  __shared__ int sM;
  __shared__ float red1[512], red2[512];
  const int c = blockIdx.x >> 2;
  const int part = blockIdx.x & 3;
  const int t = threadIdx.x;
  const int lane = t & 63;
  const int wv = t >> 6;
  for (int i = t; i < NN; i += 512) slab[i] = labels[i];
  __syncthreads();
  for (int ch = wv; ch < 64; ch += 8) {
    const unsigned long long m = __ballot(slab[ch * 64 + lane] == c);
    if (lane == 0) chunk_off[ch] = __popcll(m);
  }
  __syncthreads();
  if (wv == 0) {
    const int v = chunk_off[lane];
    int inc = v;
#pragma unroll
    for (int off = 1; off < 64; off <<= 1) {
      const int o = __shfl_up(inc, off);
      if (lane >= off) inc += o;
    }
    chunk_off[lane] = inc - v;
    if (lane == 63) sM = inc;
  }
  __syncthreads();
  const int M = sM;
  for (int ch = wv; ch < 64; ch += 8) {
    const bool my = (slab[ch * 64 + lane] == c);
    const unsigned long long m = __ballot(my);
    if (my) {
      const int pos = chunk_off[ch] + __popcll(m & ((1ULL << lane) - 1ULL));
      list[pos] = ch * 64 + lane;
    }
  }
  __syncthreads();
  const int d = (part << 7) + (t & 127);
  const int sub = t >> 7;
  float s1 = 0.f, s2 = 0.f;
  int m = sub;
  for (; m + 16 <= M; m += 16) {
    float v[4];
#pragma unroll
    for (int e = 0; e < 4; ++e) v[e] = feats[(size_t)list[m + 4 * e] * DD + d];
#pragma unroll
    for (int e = 0; e < 4; ++e) { s1 += v[e]; s2 += v[e] * v[e]; }
  }
  for (; m < M; m += 4) {
    const float v = feats[(size_t)list[m] * DD + d];
    s1 += v; s2 += v * v;
  }
  red1[t] = s1;
  red2[t] = s2;
  __syncthreads();
  float var = 0.f;
  if (t < 128) {
    const float a1 = red1[t] + red1[t + 128] + red1[t + 256] + red1[t + 384];
    const float a2 = red2[t] + red2[t + 128] + red2[t + 256] + red2[t + 384];
    const float den = fmaxf((float)M, 1.f);
    const float mean = a1 / den;
    var = fmaxf(a2 / den - mean * mean, 0.f);
    cmean[c * DD + d] = mean;
  }
  __syncthreads();
  if (t < 128) red1[t] = var;
  __syncthreads();
  for (int s = 64; s > 0; s >>= 1) {
    if (t < s) red1[t] += red1[t + s];
    __syncthreads();
  }
  if (t == 0) {
    pvar[(c << 2) + part] = red1[0];
    if (part == 0) counts[c] = (float)M;
  }
}

// ---------------- kernel 2: per-row transform ----------------
__global__ __launch_bounds__(256) void k_row(
    const float* __restrict__ feats, const int* __restrict__ labels,
    const float* __restrict__ cmean, unsigned short* __restrict__ fb,
    float* __restrict__ sqb, float* __restrict__ cd2) {
  const int w = threadIdx.x >> 6;
  const int lane = threadIdx.x & 63;
  const int row = blockIdx.x * 4 + w;
  const int lab = labels[row];
  const float4* fr = (const float4*)(feats + (size_t)row * DD);
  const float4* cm = (const float4*)(cmean + (size_t)lab * DD);
  float sq = 0.f, c2 = 0.f;
  unsigned int ob[4];
#pragma unroll
  for (int h = 0; h < 2; ++h) {
    const float4 f = fr[lane * 2 + h];
    const float4 cv = cm[lane * 2 + h];
    const float fe[4] = {f.x, f.y, f.z, f.w};
    const float ce[4] = {cv.x, cv.y, cv.z, cv.w};
    unsigned short us[4];
#pragma unroll
    for (int e = 0; e < 4; ++e) {
      const __bf16 b = (__bf16)fe[e];
      const float bf = (float)b;
      sq += bf * bf;
      const float dd = fe[e] - ce[e];
      c2 += dd * dd;
      us[e] = __builtin_bit_cast(unsigned short, b);
    }
    ob[h * 2]     = (unsigned int)us[0] | ((unsigned int)us[1] << 16);
    ob[h * 2 + 1] = (unsigned int)us[2] | ((unsigned int)us[3] << 16);
  }
  *(uint4*)(fb + (size_t)row * DD + lane * 8) = make_uint4(ob[0], ob[1], ob[2], ob[3]);
#pragma unroll
  for (int off = 32; off > 0; off >>= 1) {
    sq += __shfl_xor(sq, off);
    c2 += __shfl_xor(c2, off);
  }
  if (lane == 0) {
    sqb[row] = sq;
    cd2[row] = c2;
  }
}

// ---------------- kernel 3: fused Gram, 128x256 / 4 waves / 2 blocks-per-CU --
__global__ __launch_bounds__(256, 2) void k_gemm(
    const unsigned short* __restrict__ fb, const float* __restrict__ sqb,
    const int* __restrict__ labels,
    float* __restrict__ php, float* __restrict__ phn,
    float* __restrict__ pst, float* __restrict__ pss) {
  __shared__ __align__(16) unsigned short sA[2][128 * 32];  // 16KB
  __shared__ __align__(16) unsigned short sB[2][256 * 32];  // 32KB
  __shared__ int s_labi[128], s_labj[256];
  __shared__ float s_sqi[128], s_sqj[256];
  __shared__ float s_pad[1024];  // 4KB pad -> 55KB total -> max 2 blocks/CU

  const int bid = blockIdx.x;
  // XCD map: xcd owns 8(ib) x 8(jb): A 1MB + B 2MB = 3MB < 4MiB L2.
  const int xcd = bid & 7;
  const int w8 = bid >> 3;  // 0..63
  const int ib = ((xcd & 3) << 3) + (w8 & 7);     // 0..31
  const int jb = ((xcd >> 2) << 3) + (w8 >> 3);   // 0..15
  const int ibase = ib << 7, jbase = jb << 8;
  const int t = threadIdx.x;
  const int lane = t & 63;
  const int wn = t >> 6;          // 0..3 (col quarter)
  const int rin = lane & 15;
  const int g4 = lane >> 4;
  if (s_labj[0] == 0x7fffffff) s_pad[0] = 1.f;  // keep pad alive (never true)
  const int koffr = (g4 ^ ((rin >> 1) & 3)) << 4;  // swizzled 16B chunk in 64B row
  const int bbase = ((wn << 6) + rin) << 6;        // B row*64 bytes (col group)

  if (t < 128) {
    s_labi[t] = labels[ibase + t];
    s_sqi[t] = sqb[ibase + t];
  }
  {
    s_labj[t] = labels[jbase + t];
    s_sqj[t] = sqb[jbase + t];
  }

  // staging descriptors: 2 A-chunks + 4 B-chunks per thread (BK=32, 16B chunks)
  const unsigned short* gA[2];
  const unsigned short* gB[4];
  int loA[2], loB[4];
#pragma unroll
  for (int r = 0; r < 2; ++r) {
    const int q = (r << 8) + t;       // 0..511
    const int row = q >> 2;           // 0..127
    const int ch = q & 3;
    const int koff = (ch ^ ((row >> 1) & 3)) << 3;
    gA[r] = fb + (size_t)(ibase + row) * DD + koff;
    loA[r] = q << 3;
  }
#pragma unroll
  for (int r = 0; r < 4; ++r) {
    const int q = (r << 8) + t;       // 0..1023
    const int row = q >> 2;           // 0..255
    const int ch = q & 3;
    const int koff = (ch ^ ((row >> 1) & 3)) << 3;
    gB[r] = fb + (size_t)(jbase + row) * DD + koff;
    loB[r] = q << 3;
  }

  f32x4 acc[8][4];
#pragma unroll
  for (int mi = 0; mi < 8; ++mi)
#pragma unroll
    for (int nj = 0; nj < 4; ++nj)
      acc[mi][nj] = (f32x4){0.f, 0.f, 0.f, 0.f};

  // prologue: stage kt=0 into buf 0 (6 loads)
#pragma unroll
  for (int r = 0; r < 2; ++r) gload_lds16(gA[r], &sA[0][loA[r]]);
#pragma unroll
  for (int r = 0; r < 4; ++r) gload_lds16(gB[r], &sB[0][loB[r]]);

#pragma unroll
  for (int kt = 0; kt < 16; ++kt) {
    const int cur = kt & 1;
    if (kt < 15) {
      const int nk = (kt + 1) << 5;
#pragma unroll
      for (int r = 0; r < 2; ++r) gload_lds16(gA[r] + nk, &sA[cur ^ 1][loA[r]]);
#pragma unroll
      for (int r = 0; r < 4; ++r) gload_lds16(gB[r] + nk, &sB[cur ^ 1][loB[r]]);
      asm volatile("s_waitcnt vmcnt(6)" ::: "memory");  // STAGE(kt) landed
    } else {
      asm volatile("s_waitcnt vmcnt(0)" ::: "memory");
    }
    __builtin_amdgcn_s_barrier();
    const char* A = (const char*)sA[cur];
    const char* B = (const char*)sB[cur];
    bf16x8 af[8], bg[4];
#pragma unroll
    for (int mi = 0; mi < 8; ++mi)
      af[mi] = *(const bf16x8*)(A + (((mi << 4) + rin) << 6) + koffr);
#pragma unroll
    for (int nj = 0; nj < 4; ++nj)
      bg[nj] = *(const bf16x8*)(B + bbase + (nj << 10) + koffr);
#pragma unroll
    for (int mi = 0; mi < 8; ++mi)
#pragma unroll
      for (int nj = 0; nj < 4; ++nj)
        acc[mi][nj] = __builtin_amdgcn_mfma_f32_16x16x32_bf16(
            af[mi], bg[nj], acc[mi][nj], 0, 0, 0);
    if (kt < 15) {
      asm volatile("s_waitcnt lgkmcnt(0)" ::: "memory");
      __builtin_amdgcn_s_barrier();  // buf(kt) reusable
    }
  }

  // epilogue. i = ibase + mi*16 + g4*4 + r; j = jbase + wn*64 + nj*16 + rin.
  float qj[4];
  int lj[4];
#pragma unroll
  for (int nj = 0; nj < 4; ++nj) {
    const int cl = (wn << 6) + (nj << 4) + rin;
    qj[nj] = s_sqj[cl];
    lj[nj] = s_labj[cl];
  }
  const int jidx = (jb << 2) + wn;  // 0..63
#pragma unroll
  for (int mi = 0; mi < 8; ++mi) {
#pragma unroll
    for (int r = 0; r < 4; ++r) {
      const int rl = (mi << 4) + (g4 << 2) + r;  // 0..127
      const float qi = s_sqi[rl];
      const int li = s_labi[rl];
      float hp = 0.f, hn = 1e30f, st = 0.f, ss = 0.f;
#pragma unroll
      for (int nj = 0; nj < 4; ++nj) {
        const float g = acc[mi][nj][r];
        float d2 = qi + qj[nj] - 2.f * g;
        d2 = fmaxf(d2, 0.f);
        const float dist = sqrtf(d2);
        const bool same = (li == lj[nj]);
        const float dp = same ? dist : 0.f;
        hp = fmaxf(hp, dp);
        hn = fminf(hn, same ? 1e30f : dist);
        st += dist;
        ss += dp;
      }
#pragma unroll
      for (int off = 1; off < 16; off <<= 1) {
        hp = fmaxf(hp, __shfl_xor(hp, off));
        hn = fminf(hn, __shfl_xor(hn, off));
        st += __shfl_xor(st, off);
        ss += __shfl_xor(ss, off);
      }
      if (rin == 0) {
        const int grow = ibase + rl;
        php[jidx * NN + grow] = hp;
        phn[jidx * NN + grow] = hn;
        pst[jidx * NN + grow] = st;
        pss[jidx * NN + grow] = ss;
      }
    }
  }
}

// ---------------- kernel 4: combine partials (wave-per-row over jidx) --------
__global__ __launch_bounds__(1024) void k_fin1(
    const int* __restrict__ labels, const float* __restrict__ counts,
    const float* __restrict__ pvar, const float* __restrict__ cd2,
    const float* __restrict__ php, const float* __restrict__ phn,
    const float* __restrict__ pst, const float* __restrict__ pss,
    float* __restrict__ pf) {
  const int t = threadIdx.x;
  const int wv = t >> 6;
  const int lane = t & 63;
  const int row = blockIdx.x * 16 + wv;
  const size_t idx = (size_t)lane * NN + row;
  float hp = php[idx];
  float hn = phn[idx];
  float st = pst[idx];
  float ss = pss[idx];
#pragma unroll
  for (int off = 1; off < 64; off <<= 1) {
    hp = fmaxf(hp, __shfl_xor(hp, off));
    hn = fminf(hn, __shfl_xor(hn, off));
    st += __shfl_xor(st, off);
    ss += __shfl_xor(ss, off);
  }
  __shared__ float r1[16], r2[16];
  if (lane == 0) {
    const int lab = labels[row];
    const float cnt = counts[lab];
    const float pos = cnt - 1.f;
    const float neg = (float)NN - cnt;
    const float mean_pos = ss / fmaxf(pos, 1.f);
    const float mean_neg = (st - ss) / fmaxf(neg, 1.f);
    const float c2 = cd2[row];
    const float cdist = (c2 > 0.f) ? sqrtf(c2) : 0.f;
    const float uncert = (pvar[lab * 4] + pvar[lab * 4 + 1] +
                          pvar[lab * 4 + 2] + pvar[lab * 4 + 3]) * (1.f / 512.f);
    const float margin = 0.1f + 0.1f * (mean_neg - mean_pos) + 0.1f * (cdist * uncert);
    const float ps = fmaxf(hp - hn + margin, 0.f);
    const bool valid = (pos > 0.f) && (neg > 0.f);
    r1[wv] = valid ? ps : 0.f;
    r2[wv] = valid ? 1.f : 0.f;
  }
  __syncthreads();
  if (t == 0) {
    float s = 0.f, c = 0.f;
#pragma unroll
    for (int k = 0; k < 16; ++k) { s += r1[k]; c += r2[k]; }
    pf[2 * blockIdx.x] = s;
    pf[2 * blockIdx.x + 1] = c;
  }
}

// ---------------- kernel 5: final scalar (256 pairs) ----------------
__global__ __launch_bounds__(256) void k_fin2(const float* __restrict__ pf,
                                              float* __restrict__ out) {
  const int t = threadIdx.x;
  const int lane = t & 63;
  const int w = t >> 6;
  float s = pf[2 * t];
  float c = pf[2 * t + 1];
#pragma unroll
  for (int off = 1; off < 64; off <<= 1) {
    s += __shfl_xor(s, off);
    c += __shfl_xor(c, off);
  }
  __shared__ float ws1[4], ws2[4];
  if (lane == 0) { ws1[w] = s; ws2[w] = c; }
  __syncthreads();
  if (t == 0) {
    s = ws1[0] + ws1[1] + ws1[2] + ws1[3];
    c = ws2[0] + ws2[1] + ws2[2] + ws2[3];
    out[0] = (c > 0.f) ? (s / fmaxf(c, 1.f)) : 0.f;
  }
}

extern "C" void kernel_launch(void* const* d_in, const int* in_sizes, int n_in,
                              void* d_out, int out_size, void* d_ws, size_t ws_size,
                              hipStream_t stream) {
  (void)in_sizes; (void)n_in; (void)out_size; (void)ws_size;
  const float* feats = (const float*)d_in[0];
  const int* labels = (const int*)d_in[1];
  char* w = (char*)d_ws;
  float* counts = (float*)(w + 0);
  float* pvar   = (float*)(w + 1024);
  float* sqb    = (float*)(w + 2048);
  float* cd2    = (float*)(w + 18432);
  float* pf     = (float*)(w + 34816);
  float* cmean  = (float*)(w + 36864);
  unsigned short* fb = (unsigned short*)(w + 167936);
  float* php = (float*)(w + 4362240);           // [64][4096]
  float* phn = (float*)(w + 5410816);
  float* pst = (float*)(w + 6459392);
  float* pss = (float*)(w + 7507968);

  k_stats<<<dim3(256), dim3(512), 0, stream>>>(feats, labels, counts, cmean, pvar);
  k_row<<<dim3(1024), dim3(256), 0, stream>>>(feats, labels, cmean, fb, sqb, cd2);
  k_gemm<<<dim3(512), dim3(256), 0, stream>>>(fb, sqb, labels, php, phn, pst, pss);
  k_fin1<<<dim3(256), dim3(1024), 0, stream>>>(labels, counts, pvar, cd2,
                                               php, phn, pst, pss, pf);
  k_fin2<<<dim3(1), dim3(256), 0, stream>>>(pf, (float*)d_out);
}

// Round 14
// 54.426 us; speedup vs baseline: 1.1128x; 1.1128x over previous
//
#include <hip/hip_runtime.h>
#include <hip/hip_bf16.h>

// AdaptiveTripletLoss on MI355X (gfx950).
// R14: (a) k_gemm reverted to R9 256x256/8-wave (probe-best main loop 22us);
// (b) epilogue rin-reduce via DPP row_ror (VALU) instead of 512 ds_bpermute
// per thread (shfl) -- removes the LDS-pipe epilogue serialization;
// (c) k_stats || k_row fused into grid-partitioned k_prep (fb/sqb don't need
// cmean); cd2 moved into fin1 (reads feats+cmean there). 4 launches total.

#define NN 4096
#define DD 512
#define NCLS 64

typedef __bf16 bf16x8 __attribute__((ext_vector_type(8)));
typedef float f32x4 __attribute__((ext_vector_type(4)));

__device__ __forceinline__ void gload_lds16(const void* g, void* l) {
  __builtin_amdgcn_global_load_lds(
      (const __attribute__((address_space(1))) void*)g,
      (__attribute__((address_space(3))) void*)l, 16, 0, 0);
}

template <int CTRL>
__device__ __forceinline__ float dppf(float v) {
  return __builtin_bit_cast(float,
      __builtin_amdgcn_update_dpp(0, __builtin_bit_cast(int, v),
                                  CTRL, 0xf, 0xf, false));
}
// reduce (max,min,sum,sum) over each 16-lane DPP row via row_ror 8/4/2/1
#define ROR_STEP(CTRL)                    \
  hp = fmaxf(hp, dppf<CTRL>(hp));         \
  hn = fminf(hn, dppf<CTRL>(hn));         \
  st += dppf<CTRL>(st);                   \
  ss += dppf<CTRL>(ss);

// ---------------- kernel 1: fused class-stats (256 blk) || fb/sqb (512 blk) --
__global__ __launch_bounds__(512) void k_prep(
    const float* __restrict__ feats, const int* __restrict__ labels,
    float* __restrict__ counts, float* __restrict__ cmean,
    float* __restrict__ pvar, unsigned short* __restrict__ fb,
    float* __restrict__ sqb) {
  __shared__ __align__(16) int slab[NN];
  __shared__ int list[NN];
  __shared__ int chunk_off[64];
  __shared__ int sM;
  __shared__ float red1[512], red2[512];
  const int t = threadIdx.x;
  const int lane = t & 63;
  const int wv = t >> 6;
  if (blockIdx.x < 256) {
    // ---- class stats: block = (class c, part p) ----
    const int c = blockIdx.x >> 2;
    const int part = blockIdx.x & 3;
    for (int i = t; i < NN; i += 512) slab[i] = labels[i];
    __syncthreads();
    for (int ch = wv; ch < 64; ch += 8) {
      const unsigned long long m = __ballot(slab[ch * 64 + lane] == c);
      if (lane == 0) chunk_off[ch] = __popcll(m);
    }
    __syncthreads();
    if (wv == 0) {
      const int v = chunk_off[lane];
      int inc = v;
#pragma unroll
      for (int off = 1; off < 64; off <<= 1) {
        const int o = __shfl_up(inc, off);
        if (lane >= off) inc += o;
      }
      chunk_off[lane] = inc - v;
      if (lane == 63) sM = inc;
    }
    __syncthreads();
    const int M = sM;
    for (int ch = wv; ch < 64; ch += 8) {
      const bool my = (slab[ch * 64 + lane] == c);
      const unsigned long long m = __ballot(my);
      if (my) {
        const int pos = chunk_off[ch] + __popcll(m & ((1ULL << lane) - 1ULL));
        list[pos] = ch * 64 + lane;
      }
    }
    __syncthreads();
    const int d = (part << 7) + (t & 127);
    const int sub = t >> 7;
    float s1 = 0.f, s2 = 0.f;
    int m = sub;
    for (; m + 16 <= M; m += 16) {
      float v[4];
#pragma unroll
      for (int e = 0; e < 4; ++e) v[e] = feats[(size_t)list[m + 4 * e] * DD + d];
#pragma unroll
      for (int e = 0; e < 4; ++e) { s1 += v[e]; s2 += v[e] * v[e]; }
    }
    for (; m < M; m += 4) {
      const float v = feats[(size_t)list[m] * DD + d];
      s1 += v; s2 += v * v;
    }
    red1[t] = s1;
    red2[t] = s2;
    __syncthreads();
    float var = 0.f;
    if (t < 128) {
      const float a1 = red1[t] + red1[t + 128] + red1[t + 256] + red1[t + 384];
      const float a2 = red2[t] + red2[t + 128] + red2[t + 256] + red2[t + 384];
      const float den = fmaxf((float)M, 1.f);
      const float mean = a1 / den;
      var = fmaxf(a2 / den - mean * mean, 0.f);  // biased variance
      cmean[c * DD + d] = mean;
    }
    __syncthreads();
    if (t < 128) red1[t] = var;
    __syncthreads();
    for (int s = 64; s > 0; s >>= 1) {
      if (t < s) red1[t] += red1[t + s];
      __syncthreads();
    }
    if (t == 0) {
      pvar[(c << 2) + part] = red1[0];
      if (part == 0) counts[c] = (float)M;
    }
  } else {
    // ---- per-row fb/sqb: wave per row (no cmean dependency) ----
    const int row = (blockIdx.x - 256) * 8 + wv;
    const float4* fr = (const float4*)(feats + (size_t)row * DD);
    float sq = 0.f;
    unsigned int ob[4];
#pragma unroll
    for (int h = 0; h < 2; ++h) {
      const float4 f = fr[lane * 2 + h];
      const float fe[4] = {f.x, f.y, f.z, f.w};
      unsigned short us[4];
#pragma unroll
      for (int e = 0; e < 4; ++e) {
        const __bf16 b = (__bf16)fe[e];
        const float bf = (float)b;
        sq += bf * bf;
        us[e] = __builtin_bit_cast(unsigned short, b);
      }
      ob[h * 2]     = (unsigned int)us[0] | ((unsigned int)us[1] << 16);
      ob[h * 2 + 1] = (unsigned int)us[2] | ((unsigned int)us[3] << 16);
    }
    *(uint4*)(fb + (size_t)row * DD + lane * 8) = make_uint4(ob[0], ob[1], ob[2], ob[3]);
#pragma unroll
    for (int off = 32; off > 0; off >>= 1) sq += __shfl_xor(sq, off);
    if (lane == 0) sqb[row] = sq;
  }
}

// ---------------- kernel 2: fused Gram, 256x256 / 8 waves (R9) ----------------
__global__ __launch_bounds__(512, 2) void k_gemm(
    const unsigned short* __restrict__ fb, const float* __restrict__ sqb,
    const int* __restrict__ labels,
    float* __restrict__ php, float* __restrict__ phn,
    float* __restrict__ pst, float* __restrict__ pss) {
  __shared__ __align__(16) unsigned short sA[2][256 * 64];
  __shared__ __align__(16) unsigned short sB[2][256 * 64];
  __shared__ int s_labi[256], s_labj[256];
  __shared__ float s_sqi[256], s_sqj[256];

  const int bid = blockIdx.x;
  const int xcd = bid & 7;
  const int w8 = bid >> 3;
  const int ib = ((xcd & 3) << 2) + (w8 & 3);
  const int jb = ((xcd >> 2) << 3) + (w8 >> 2);
  const int ibase = ib << 8, jbase = jb << 8;
  const int t = threadIdx.x;
  const int lane = t & 63;
  const int w = t >> 6;
  const int wm = w >> 2;
  const int wn = w & 3;
  const int rin = lane & 15;
  const int g4 = lane >> 4;
  const int swzbyte = (g4 ^ (rin & 7)) << 4;
  const int abase = ((wm << 7) + rin) << 7;
  const int bbase = ((wn << 6) + rin) << 7;

  if (t < 256) {
    s_labi[t] = labels[ibase + t];
    s_labj[t] = labels[jbase + t];
    s_sqi[t] = sqb[ibase + t];
    s_sqj[t] = sqb[jbase + t];
  }

  const unsigned short* gA[4];
  const unsigned short* gB[4];
  int lo[4];
#pragma unroll
  for (int r = 0; r < 4; ++r) {
    const int q = (r << 9) + t;
    const int row = q >> 3;
    const int ch = q & 7;
    const int koff = (ch ^ (row & 7)) << 3;
    gA[r] = fb + (size_t)(ibase + row) * DD + koff;
    gB[r] = fb + (size_t)(jbase + row) * DD + koff;
    lo[r] = q << 3;
  }

  f32x4 acc[8][4];
#pragma unroll
  for (int mi = 0; mi < 8; ++mi)
#pragma unroll
    for (int nj = 0; nj < 4; ++nj)
      acc[mi][nj] = (f32x4){0.f, 0.f, 0.f, 0.f};

#pragma unroll
  for (int r = 0; r < 4; ++r) {
    gload_lds16(gA[r], &sA[0][lo[r]]);
    gload_lds16(gB[r], &sB[0][lo[r]]);
  }

#pragma unroll
  for (int kt = 0; kt < 8; ++kt) {
    const int cur = kt & 1;
    if (kt < 7) {
#pragma unroll
      for (int r = 0; r < 4; ++r) {
        gload_lds16(gA[r] + ((kt + 1) << 6), &sA[cur ^ 1][lo[r]]);
        gload_lds16(gB[r] + ((kt + 1) << 6), &sB[cur ^ 1][lo[r]]);
      }
      asm volatile("s_waitcnt vmcnt(8)" ::: "memory");  // STAGE(kt) landed
    } else {
      asm volatile("s_waitcnt vmcnt(0)" ::: "memory");
    }
    __builtin_amdgcn_s_barrier();
    const char* A = (const char*)sA[cur];
    const char* B = (const char*)sB[cur];
#pragma unroll
    for (int ks = 0; ks < 2; ++ks) {
      bf16x8 af[8], bg[4];
#pragma unroll
      for (int mi = 0; mi < 8; ++mi)
        af[mi] = *(const bf16x8*)(A + abase + (mi << 11) + (swzbyte ^ (ks << 6)));
#pragma unroll
      for (int nj = 0; nj < 4; ++nj)
        bg[nj] = *(const bf16x8*)(B + bbase + (nj << 11) + (swzbyte ^ (ks << 6)));
#pragma unroll
      for (int mi = 0; mi < 8; ++mi)
#pragma unroll
        for (int nj = 0; nj < 4; ++nj)
          acc[mi][nj] = __builtin_amdgcn_mfma_f32_16x16x32_bf16(
              af[mi], bg[nj], acc[mi][nj], 0, 0, 0);
    }
    if (kt < 7) {
      asm volatile("s_waitcnt lgkmcnt(0)" ::: "memory");
      __builtin_amdgcn_s_barrier();
    }
  }

  // epilogue. i = wm*128 + mi*16 + g4*4 + r, j = wn*64 + nj*16 + rin.
  // rin-reduce via DPP row_ror (VALU) -- no DS traffic.
  float qj[4];
  int lj[4];
#pragma unroll
  for (int nj = 0; nj < 4; ++nj) {
    const int cl = (wn << 6) + (nj << 4) + rin;
    qj[nj] = s_sqj[cl];
    lj[nj] = s_labj[cl];
  }
  const int jidx = (jb << 2) + wn;
#pragma unroll
  for (int mi = 0; mi < 8; ++mi) {
#pragma unroll
    for (int r = 0; r < 4; ++r) {
      const int rl = (wm << 7) + (mi << 4) + (g4 << 2) + r;
      const float qi = s_sqi[rl];
      const int li = s_labi[rl];
      float hp = 0.f, hn = 1e30f, st = 0.f, ss = 0.f;
#pragma unroll
      for (int nj = 0; nj < 4; ++nj) {
        const float g = acc[mi][nj][r];
        float d2 = qi + qj[nj] - 2.f * g;
        d2 = fmaxf(d2, 0.f);
        const float dist = sqrtf(d2);
        const bool same = (li == lj[nj]);
        const float dp = same ? dist : 0.f;
        hp = fmaxf(hp, dp);
        hn = fminf(hn, same ? 1e30f : dist);
        st += dist;
        ss += dp;
      }
      ROR_STEP(0x128)  // ror:8
      ROR_STEP(0x124)  // ror:4
      ROR_STEP(0x122)  // ror:2
      ROR_STEP(0x121)  // ror:1
      if (rin == 0) {
        const int grow = ibase + rl;
        php[jidx * NN + grow] = hp;
        phn[jidx * NN + grow] = hn;
        pst[jidx * NN + grow] = st;
        pss[jidx * NN + grow] = ss;
      }
    }
  }
}

// ---------------- kernel 3: combine partials + cd2 + per-row margin ----------
__global__ __launch_bounds__(1024) void k_fin1(
    const int* __restrict__ labels, const float* __restrict__ counts,
    const float* __restrict__ pvar, const float* __restrict__ feats,
    const float* __restrict__ cmean,
    const float* __restrict__ php, const float* __restrict__ phn,
    const float* __restrict__ pst, const float* __restrict__ pss,
    float* __restrict__ pf) {
  const int t = threadIdx.x;
  const int wv = t >> 6;
  const int lane = t & 63;
  const int row = blockIdx.x * 16 + wv;
  const int lab = labels[row];
  // cd2 = ||f_row - cmean[lab]||^2 (fp32 exact), 8 dims/lane
  const float4* fr = (const float4*)(feats + (size_t)row * DD);
  const float4* cm = (const float4*)(cmean + (size_t)lab * DD);
  float c2 = 0.f;
#pragma unroll
  for (int h = 0; h < 2; ++h) {
    const float4 f = fr[lane * 2 + h];
    const float4 c = cm[lane * 2 + h];
    const float d0 = f.x - c.x, d1 = f.y - c.y, d2_ = f.z - c.z, d3 = f.w - c.w;
    c2 += d0 * d0 + d1 * d1 + d2_ * d2_ + d3 * d3;
  }
  const size_t idx = (size_t)lane * NN + row;
  float hp = php[idx];
  float hn = phn[idx];
  float st = pst[idx];
  float ss = pss[idx];
#pragma unroll
  for (int off = 1; off < 64; off <<= 1) {
    hp = fmaxf(hp, __shfl_xor(hp, off));
    hn = fminf(hn, __shfl_xor(hn, off));
    st += __shfl_xor(st, off);
    ss += __shfl_xor(ss, off);
    c2 += __shfl_xor(c2, off);
  }
  __shared__ float r1[16], r2[16];
  if (lane == 0) {
    const float cnt = counts[lab];
    const float pos = cnt - 1.f;
    const float neg = (float)NN - cnt;
    const float mean_pos = ss / fmaxf(pos, 1.f);
    const float mean_neg = (st - ss) / fmaxf(neg, 1.f);
    const float cdist = (c2 > 0.f) ? sqrtf(c2) : 0.f;
    const float uncert = (pvar[lab * 4] + pvar[lab * 4 + 1] +
                          pvar[lab * 4 + 2] + pvar[lab * 4 + 3]) * (1.f / 512.f);
    const float margin = 0.1f + 0.1f * (mean_neg - mean_pos) + 0.1f * (cdist * uncert);
    const float ps = fmaxf(hp - hn + margin, 0.f);
    const bool valid = (pos > 0.f) && (neg > 0.f);
    r1[wv] = valid ? ps : 0.f;
    r2[wv] = valid ? 1.f : 0.f;
  }
  __syncthreads();
  if (t == 0) {
    float s = 0.f, c = 0.f;
#pragma unroll
    for (int k = 0; k < 16; ++k) { s += r1[k]; c += r2[k]; }
    pf[2 * blockIdx.x] = s;
    pf[2 * blockIdx.x + 1] = c;
  }
}

// ---------------- kernel 4: final scalar (256 pairs) ----------------
__global__ __launch_bounds__(256) void k_fin2(const float* __restrict__ pf,
                                              float* __restrict__ out) {
  const int t = threadIdx.x;
  const int lane = t & 63;
  const int w = t >> 6;
  float s = pf[2 * t];
  float c = pf[2 * t + 1];
#pragma unroll
  for (int off = 1; off < 64; off <<= 1) {
    s += __shfl_xor(s, off);
    c += __shfl_xor(c, off);
  }
  __shared__ float ws1[4], ws2[4];
  if (lane == 0) { ws1[w] = s; ws2[w] = c; }
  __syncthreads();
  if (t == 0) {
    s = ws1[0] + ws1[1] + ws1[2] + ws1[3];
    c = ws2[0] + ws2[1] + ws2[2] + ws2[3];
    out[0] = (c > 0.f) ? (s / fmaxf(c, 1.f)) : 0.f;
  }
}

extern "C" void kernel_launch(void* const* d_in, const int* in_sizes, int n_in,
                              void* d_out, int out_size, void* d_ws, size_t ws_size,
                              hipStream_t stream) {
  (void)in_sizes; (void)n_in; (void)out_size; (void)ws_size;
  const float* feats = (const float*)d_in[0];
  const int* labels = (const int*)d_in[1];
  char* w = (char*)d_ws;
  float* counts = (float*)(w + 0);
  float* pvar   = (float*)(w + 1024);           // 256 floats
  float* sqb    = (float*)(w + 2048);
  float* pf     = (float*)(w + 34816);          // 512 floats
  float* cmean  = (float*)(w + 36864);
  unsigned short* fb = (unsigned short*)(w + 167936);
  float* php = (float*)(w + 4362240);           // [64][4096]
  float* phn = (float*)(w + 5410816);
  float* pst = (float*)(w + 6459392);
  float* pss = (float*)(w + 7507968);

  k_prep<<<dim3(768), dim3(512), 0, stream>>>(feats, labels, counts, cmean,
                                              pvar, fb, sqb);
  k_gemm<<<dim3(256), dim3(512), 0, stream>>>(fb, sqb, labels, php, phn, pst, pss);
  k_fin1<<<dim3(256), dim3(1024), 0, stream>>>(labels, counts, pvar, feats,
                                               cmean, php, phn, pst, pss, pf);
  k_fin2<<<dim3(1), dim3(256), 0, stream>>>(pf, (float*)d_out);
}